// Round 10
// baseline (105.512 us; speedup 1.0000x reference)
//
#include <hip/hip_runtime.h>
#include <hip/hip_bf16.h>

// MHA: B=2, S=2048, D=1024, H=16, Dh=64, causal band window 256.
// Fused cvt; QKV GEMM = 256x128-tile 4-wave fine-4-phase pipeline (3-slot LDS
// ring, dual barrier per phase, setprio around MFMA, end-of-iter vmcnt(6),
// 2 blocks/CU, grid 384); banded flash attention (static-max softmax);
// out-proj = r4-proven 2-phase 128x64.
// r9 lesson: coarse 1-barrier/iter 256^2 at 1 block/CU on 192/256 CUs = 568TF
// (m196 anti-pattern). This round: fine interleave + full CU coverage.

typedef __bf16 bf16x8 __attribute__((ext_vector_type(8)));
typedef float f32x4 __attribute__((ext_vector_type(4)));
typedef short s16x4 __attribute__((ext_vector_type(4)));
typedef unsigned short u16x8 __attribute__((ext_vector_type(8)));
typedef unsigned short u16x4 __attribute__((ext_vector_type(4)));

__device__ __forceinline__ unsigned short f2bf(float f) {
  unsigned int u = __builtin_bit_cast(unsigned int, f);
  u += 0x7FFFu + ((u >> 16) & 1u);   // round-to-nearest-even
  return (unsigned short)(u >> 16);
}

__device__ __forceinline__ f32x4 mfma32(bf16x8 a, bf16x8 b, f32x4 c) {
  return __builtin_amdgcn_mfma_f32_16x16x32_bf16(a, b, c, 0, 0, 0);
}
__device__ __forceinline__ f32x4 mfma16(s16x4 a, s16x4 b, f32x4 c) {
  return __builtin_amdgcn_mfma_f32_16x16x16bf16_1k(a, b, c, 0, 0, 0);
}

// async global->LDS, 16B per lane. LDS dest must be wave-uniform base
// (HW adds lane*16); global src is per-lane.
__device__ __forceinline__ void gl16(const unsigned short* gsrc,
                                     unsigned short* lds) {
  __builtin_amdgcn_global_load_lds(
      (const __attribute__((address_space(1))) unsigned int*)gsrc,
      (__attribute__((address_space(3))) unsigned int*)lds, 16, 0, 0);
}

__device__ __forceinline__ void rawbar() {
  asm volatile("s_barrier" ::: "memory");
}
__device__ __forceinline__ void lgkm0() {
  asm volatile("s_waitcnt lgkmcnt(0)" ::: "memory");
}

// ---- fused converts: z<4 -> Wt[z][n][k] = bf16(W[k][n]); z==4 -> X->bf16 ---
__global__ __launch_bounds__(256) void cvt_all(
    const float* __restrict__ x,
    const float* __restrict__ Wq, const float* __restrict__ Wk,
    const float* __restrict__ Wv, const float* __restrict__ Wo,
    unsigned short* __restrict__ xb, unsigned short* __restrict__ Wt) {
  const int z = blockIdx.z;
  const int tx = threadIdx.x, ty = threadIdx.y;    // 32 x 8
  if (z == 4) {
    const int tid = (blockIdx.y * 32 + blockIdx.x) * 256 + ty * 32 + tx;
#pragma unroll
    for (int it = 0; it < 4; ++it) {
      const int i = tid + it * 262144;
      const float4 v = ((const float4*)x)[i];
      u16x4 o = { f2bf(v.x), f2bf(v.y), f2bf(v.z), f2bf(v.w) };
      *(u16x4*)(xb + (size_t)i * 4) = o;
    }
    return;
  }
  const float* W = (z == 0) ? Wq : (z == 1) ? Wk : (z == 2) ? Wv : Wo;
  unsigned short* dst = Wt + (size_t)z * 1024 * 1024;
  __shared__ float t[32][33];
  const int n0 = blockIdx.x * 32, k0 = blockIdx.y * 32;
#pragma unroll
  for (int i = 0; i < 32; i += 8)
    t[ty + i][tx] = W[(size_t)(k0 + ty + i) * 1024 + n0 + tx];
  __syncthreads();
#pragma unroll
  for (int i = 0; i < 32; i += 8)
    dst[(size_t)(n0 + ty + i) * 1024 + k0 + tx] = f2bf(t[tx][ty + i]);
}

// ---------------- QKV GEMM: 256x128 tile, 4 waves, fine 4-phase -------------
// C[4096,3072] = A[4096,1024] * Bt[3072,1024]^T. Grid (16,24): bn 0-7 = q,
// 8-15 = k, 16-23 = v (uniform per block).
// LDS: 3-slot ring of K-tiles (A 256x32 = 16KB, B 128x32 = 8KB) = 72KB ->
// 2 blocks/CU. Stage: 6 gl16/K-tile (A:4, B:2). 2-way swizzle: element
// (row, kchunk c) at chunk-field c ^ ((row>>1)&3); gl16 dest linear ->
// source pre-swizzled; proven 0 bank conflicts (r9 PMC).
// Schedule per iter t (slot s=t%3, stage tile t+2 -> (s+2)%3):
//  ph0: stage A0,A1 | read am0-3,bf0-1 | bar | lgkm0 | prio1 8xMFMA prio0 | bar
//  ph1: stage A2,A3 | read bf2-3,am4-5 | bar | lgkm0 | prio1 8xMFMA prio0 | bar
//  ph2: stage B0    | read am6-7       | bar | lgkm0 | prio1 8xMFMA prio0 | bar
//  ph3: stage B1    |                    bar |         prio1 8xMFMA prio0
//       | vmcnt(6: t+1 landed, t+2 in flight) | bar
// Ring safety: slot (s+2)%3 last read at iter t-1 (closed by its ph3 bar);
// slot-s reads gated by iter t-1's trailing vmcnt+bar.
__global__ __launch_bounds__(256, 2) void gemm_qkv(
    const unsigned short* __restrict__ A, const unsigned short* __restrict__ Bt,
    const float* __restrict__ bq, const float* __restrict__ bk,
    const float* __restrict__ bv,
    unsigned short* __restrict__ q_ws, unsigned short* __restrict__ k_ws,
    unsigned short* __restrict__ v_ws) {
  __shared__ __align__(16) unsigned short Alds[3][8192];   // 256x32 per slot
  __shared__ __align__(16) unsigned short Blds[3][4096];   // 128x32 per slot
  const int tid = threadIdx.x, lane = tid & 63, w = tid >> 6;
  const int lq = lane & 15, lg = lane >> 4;
  const int bm = blockIdx.x, bn = blockIdx.y;
  const int wr = (w >> 1) * 128, wc = (w & 1) * 64;    // wave tile 128x64

  // staging: inst i covers rows i*64 + srow; srow = w*16 + (lane>>2).
  // dest linear; source chunk pre-swizzled: (lane&3) ^ ((lane>>3)&3).
  const int srow = w * 16 + (lane >> 2);
  const int scs = ((lane & 3) ^ ((lane >> 3) & 3)) << 3;
  const unsigned short* Ag = A + (size_t)(bm * 256 + srow) * 1024 + scs;
  const unsigned short* Bg = Bt + (size_t)(bn * 128 + srow) * 1024 + scs;

  auto stageA = [&](int kt2, int s2, int i) {
    gl16(Ag + (size_t)i * 64 * 1024 + kt2, &Alds[s2][i * 2048 + w * 512]);
  };
  auto stageB = [&](int kt2, int s2, int i) {
    gl16(Bg + (size_t)i * 64 * 1024 + kt2, &Blds[s2][i * 2048 + w * 512]);
  };

  // frag reads: (row, chunk lg) stored at chunk-field lg ^ ((lq>>1)&3).
  const int cs = (lq >> 1) & 3;
  auto rdA = [&](int s, int m) {
    return *(const bf16x8*)(&Alds[s][(wr + m * 16 + lq) * 32 +
                                     ((lg ^ cs) << 3)]);
  };
  auto rdB = [&](int s, int n) {
    return *(const bf16x8*)(&Blds[s][(wc + n * 16 + lq) * 32 +
                                     ((lg ^ cs) << 3)]);
  };

  f32x4 acc[8][4] = {};
  // prologue: stage tiles 0 (slot0) and 1 (slot1); wait tile 0.
  stageA(0, 0, 0); stageA(0, 0, 1); stageA(0, 0, 2); stageA(0, 0, 3);
  stageB(0, 0, 0); stageB(0, 0, 1);
  stageA(32, 1, 0); stageA(32, 1, 1); stageA(32, 1, 2); stageA(32, 1, 3);
  stageB(32, 1, 0); stageB(32, 1, 1);
  asm volatile("s_waitcnt vmcnt(6)" ::: "memory");
  rawbar();

  int s = 0;
  for (int t = 0; t < 32; ++t) {
    const int kt2 = (t + 2) * 32;
    const int s2 = (s == 0) ? 2 : s - 1;             // (s+2)%3
    const bool st = (t < 30);
    bf16x8 am[4], am2[4], bf[4];
    // ---- phase 0: m0-3 x n0-1
    if (st) { stageA(kt2, s2, 0); stageA(kt2, s2, 1); }
    am[0] = rdA(s, 0); am[1] = rdA(s, 1); am[2] = rdA(s, 2); am[3] = rdA(s, 3);
    bf[0] = rdB(s, 0); bf[1] = rdB(s, 1);
    rawbar(); lgkm0();
    __builtin_amdgcn_s_setprio(1);
#pragma unroll
    for (int m = 0; m < 4; ++m) {
      acc[m][0] = mfma32(am[m], bf[0], acc[m][0]);
      acc[m][1] = mfma32(am[m], bf[1], acc[m][1]);
    }
    __builtin_amdgcn_s_setprio(0);
    rawbar();
    // ---- phase 1: m0-3 x n2-3 (prefetch am4-5)
    if (st) { stageA(kt2, s2, 2); stageA(kt2, s2, 3); }
    bf[2] = rdB(s, 2); bf[3] = rdB(s, 3);
    am2[0] = rdA(s, 4); am2[1] = rdA(s, 5);
    rawbar(); lgkm0();
    __builtin_amdgcn_s_setprio(1);
#pragma unroll
    for (int m = 0; m < 4; ++m) {
      acc[m][2] = mfma32(am[m], bf[2], acc[m][2]);
      acc[m][3] = mfma32(am[m], bf[3], acc[m][3]);
    }
    __builtin_amdgcn_s_setprio(0);
    rawbar();
    // ---- phase 2: m4-5 x n0-3 (prefetch am6-7)
    if (st) stageB(kt2, s2, 0);
    am2[2] = rdA(s, 6); am2[3] = rdA(s, 7);
    rawbar(); lgkm0();
    __builtin_amdgcn_s_setprio(1);
#pragma unroll
    for (int n = 0; n < 4; ++n) {
      acc[4][n] = mfma32(am2[0], bf[n], acc[4][n]);
      acc[5][n] = mfma32(am2[1], bf[n], acc[5][n]);
    }
    __builtin_amdgcn_s_setprio(0);
    rawbar();
    // ---- phase 3: m6-7 x n0-3; end-of-iter vmcnt gate
    if (st) stageB(kt2, s2, 1);
    rawbar();
    __builtin_amdgcn_s_setprio(1);
#pragma unroll
    for (int n = 0; n < 4; ++n) {
      acc[6][n] = mfma32(am2[2], bf[n], acc[6][n]);
      acc[7][n] = mfma32(am2[3], bf[n], acc[7][n]);
    }
    __builtin_amdgcn_s_setprio(0);
    if (t < 30) asm volatile("s_waitcnt vmcnt(6)" ::: "memory");
    else if (t == 30) asm volatile("s_waitcnt vmcnt(0)" ::: "memory");
    rawbar();
    s = (s == 2) ? 0 : s + 1;
  }

  // epilogue: type uniform per block. C/D layout (m89):
  // col = lane&15 (+n*16), row = (lane>>4)*4 + reg (+m*16).
  const int ttype = bn >> 3;                       // 0=q,1=k,2=v
  const float* bias = (ttype == 0) ? bq : (ttype == 1) ? bk : bv;
  unsigned short* dst = (ttype == 0) ? q_ws : (ttype == 1) ? k_ws : v_ws;
  const float scalef = (ttype == 0) ? 0.125f : 1.0f;
  const int ccb = (bn & 7) * 128 + wc + lq;        // col within 0..1023
  const int r0 = bm * 256 + wr + lg * 4;
#pragma unroll
  for (int m = 0; m < 8; ++m) {
#pragma unroll
    for (int n = 0; n < 4; ++n) {
      const int cc = ccb + n * 16;
      const int h = cc >> 6, dh = cc & 63;
#pragma unroll
      for (int j = 0; j < 4; ++j) {
        const int row = r0 + m * 16 + j;
        const int b = row >> 11, sq = row & 2047;
        const float v = (acc[m][n][j] + bias[cc]) * scalef;
        dst[((size_t)(b * 16 + h) * 2048 + sq) * 64 + dh] = f2bf(v);
      }
    }
  }
}

// ------------- out-proj GEMM (r4-proven 2-phase 128x64, BK=32) --------------
__global__ __launch_bounds__(256) void gemm_out(
    const unsigned short* __restrict__ A, const unsigned short* __restrict__ Bt,
    const float* __restrict__ bo, float* __restrict__ outp) {
  __shared__ unsigned short Alds[128 * 32];
  __shared__ unsigned short Blds[64 * 32];
  const int tid = threadIdx.x, lane = tid & 63, w = tid >> 6;
  const int lq = lane & 15, lg = lane >> 4;
  const int bm = blockIdx.x, bn = blockIdx.y;
  const int wr = (w >> 1) * 64, wc = (w & 1) * 32;

  const int srow = lane >> 2, scol8 = (lane & 3) * 8;
  const unsigned short* Ag =
      A + (size_t)(bm * 128 + w * 32 + srow) * 1024 + scol8;
  const unsigned short* Bg =
      Bt + (size_t)(bn * 64 + w * 16 + srow) * 1024 + scol8;
  unsigned short* Al0 = Alds + (w * 32) * 32;
  unsigned short* Al1 = Alds + (w * 32 + 16) * 32;
  unsigned short* Bl0 = Blds + (w * 16) * 32;

  f32x4 acc[4][2] = {};
  for (int kt = 0; kt < 1024; kt += 32) {
    __syncthreads();
    gl16(Ag + kt, Al0);
    gl16(Ag + kt + 16 * 1024, Al1);
    gl16(Bg + kt, Bl0);
    __syncthreads();
    bf16x8 af[4], bfr[2];
#pragma unroll
    for (int m = 0; m < 4; ++m)
      af[m] = *(const bf16x8*)(Alds + (wr + m * 16 + lq) * 32 + lg * 8);
#pragma unroll
    for (int n = 0; n < 2; ++n)
      bfr[n] = *(const bf16x8*)(Blds + (wc + n * 16 + lq) * 32 + lg * 8);
#pragma unroll
    for (int m = 0; m < 4; ++m)
#pragma unroll
      for (int n = 0; n < 2; ++n)
        acc[m][n] = mfma32(af[m], bfr[n], acc[m][n]);
  }

  const int r0 = bm * 128 + wr + lg * 4;
  const int c0g = bn * 64 + wc + lq;
#pragma unroll
  for (int m = 0; m < 4; ++m)
#pragma unroll
    for (int n = 0; n < 2; ++n) {
      const int col = c0g + n * 16;
#pragma unroll
      for (int j = 0; j < 4; ++j)
        outp[(size_t)(r0 + m * 16 + j) * 1024 + col] = acc[m][n][j] + bo[col];
    }
}

// ---------------- banded flash attention (r8: static-max softmax) -----------
__global__ __launch_bounds__(256) void attn_kernel(
    const unsigned short* __restrict__ q_ws,
    const unsigned short* __restrict__ k_ws,
    const unsigned short* __restrict__ v_ws,
    unsigned short* __restrict__ attn_out) {
  __shared__ unsigned short o_lds[4][16 * 64];
  const int tid = threadIdx.x, lane = tid & 63, w = tid >> 6;
  const int lq = lane & 15, lg = lane >> 4;
  const int bh = blockIdx.y;                       // b*16 + h
  const int q0 = blockIdx.x * 64 + w * 16;
  const unsigned short* Q = q_ws + (size_t)bh * 2048 * 64;
  const unsigned short* Kp = k_ws + (size_t)bh * 2048 * 64;
  const unsigned short* Vp = v_ws + (size_t)bh * 2048 * 64;

  const bf16x8 qf0 = *(const bf16x8*)(Q + (size_t)(q0 + lq) * 64 + lg * 8);
  const bf16x8 qf1 = *(const bf16x8*)(Q + (size_t)(q0 + lq) * 64 + 32 + lg * 8);

  float lsum = 0.f;
  f32x4 oacc[4] = {};
  int t0 = (q0 - 255) >> 4;
  if (t0 < 0) t0 = 0;
  const int t1 = q0 >> 4;

  for (int t = t0; t <= t1; ++t) {
    const int j0 = t * 16;
    const bf16x8 kf0 = *(const bf16x8*)(Kp + (size_t)(j0 + lq) * 64 + lg * 8);
    const bf16x8 kf1 =
        *(const bf16x8*)(Kp + (size_t)(j0 + lq) * 64 + 32 + lg * 8);
    f32x4 stv = {};
    stv = mfma32(kf0, qf0, stv);
    stv = mfma32(kf1, qf1, stv);   // S^T: col=q=lq, row=key=j0+lg*4+reg

    float p[4], ps = 0.f;
#pragma unroll
    for (int r = 0; r < 4; ++r) {
      const int delta = (q0 + lq) - (j0 + lg * 4 + r);
      const bool ok = (delta >= 0) && (delta < 256);
      p[r] = ok ? __expf(stv[r] - 4.0f) : 0.f;
      ps += p[r];
    }
    ps += __shfl_xor(ps, 16);
    ps += __shfl_xor(ps, 32);
    lsum += ps;

    s16x4 pb = { (short)f2bf(p[0]), (short)f2bf(p[1]),
                 (short)f2bf(p[2]), (short)f2bf(p[3]) };
#pragma unroll
    for (int c = 0; c < 4; ++c) {
      s16x4 vf;
#pragma unroll
      for (int j = 0; j < 4; ++j)
        vf[j] = (short)Vp[(size_t)(j0 + lg * 4 + j) * 64 + c * 16 + lq];
      oacc[c] = mfma16(vf, pb, oacc[c]);
    }
  }

  const float rl = 1.f / lsum;
#pragma unroll
  for (int c = 0; c < 4; ++c)
#pragma unroll
    for (int r = 0; r < 4; ++r)
      o_lds[w][lq * 64 + c * 16 + lg * 4 + r] = f2bf(oacc[c][r] * rl);
  __syncthreads();
  const int row = lane >> 2, d0 = (lane & 3) * 16;
  const u16x8 o0 = *(const u16x8*)(&o_lds[w][row * 64 + d0]);
  const u16x8 o1 = *(const u16x8*)(&o_lds[w][row * 64 + d0 + 8]);
  const size_t g =
      ((size_t)((bh >> 4) * 2048 + q0 + row)) * 1024 + (bh & 15) * 64 + d0;
  *(u16x8*)(attn_out + g) = o0;
  *(u16x8*)(attn_out + g + 8) = o1;
}

// ---------------------------------------------------------------------------
extern "C" void kernel_launch(void* const* d_in, const int* in_sizes, int n_in,
                              void* d_out, int out_size, void* d_ws,
                              size_t ws_size, hipStream_t stream) {
  const float* query = (const float*)d_in[0];
  const float* Wq = (const float*)d_in[1];
  const float* bq = (const float*)d_in[2];
  const float* Wk = (const float*)d_in[3];
  const float* bk = (const float*)d_in[4];
  const float* Wv = (const float*)d_in[5];
  const float* bv = (const float*)d_in[6];
  const float* Wo = (const float*)d_in[7];
  const float* bo = (const float*)d_in[8];
  float* outp = (float*)d_out;

  char* ws = (char*)d_ws;
  unsigned short* xbf = (unsigned short*)(ws);               // 8 MiB; reused as attn_out
  unsigned short* wt  = (unsigned short*)(ws + (8u << 20));  // 8 MiB (4 weights^T)
  unsigned short* qws = (unsigned short*)(ws + (16u << 20)); // 8 MiB
  unsigned short* kws = (unsigned short*)(ws + (24u << 20)); // 8 MiB
  unsigned short* vws = (unsigned short*)(ws + (32u << 20)); // 8 MiB

  cvt_all<<<dim3(32, 32, 5), dim3(32, 8), 0, stream>>>(query, Wq, Wk, Wv, Wo,
                                                       xbf, wt);
  // fused QKV: 256x128 tiles, grid (16,24), 256 threads, 2 blocks/CU
  gemm_qkv<<<dim3(16, 24), 256, 0, stream>>>(xbf, wt, bq, bk, bv, qws, kws,
                                             vws);
  attn_kernel<<<dim3(32, 32), 256, 0, stream>>>(qws, kws, vws, xbf);
  // output projection: N = 1024, 128x64 tile -> 512 blocks (2/CU)
  gemm_out<<<dim3(32, 16), 256, 0, stream>>>(
      xbf, wt + (size_t)3 * 1024 * 1024, bo, outp);
}

// Round 11
// 95.925 us; speedup vs baseline: 1.0999x; 1.0999x over previous
//
#include <hip/hip_runtime.h>
#include <hip/hip_bf16.h>

// MHA: B=2, S=2048, D=1024, H=16, Dh=64, causal band window 256.
// Fused cvt; GEMMs = r4/r8-proven 2-phase global_load_lds structure upgraded
// with (a) BK=64 (16 iters, half the barrier drains) and (b) XOR LDS swizzle:
// element (row, kchunk kc) stored at chunk-field kc ^ (row&7) -- kills the
// 6.3M bank conflicts (2x LDS-read serialization) the BK=32 linear layout
// had (r2/r4 PMC); swizzle scheme PMC-verified 0-conflict in r9/r10.
// gl16 writes linearly -> global source pre-swizzled (rule #21 both-sides).
// banded flash attention (static-max softmax) unchanged from r8.
// History: r5 XCD swizzle & unswizzled BK=64 reverted; r7/r9/r10 deep
// pipelines all <= plain 2-phase -> direction abandoned (3 attempts).

typedef __bf16 bf16x8 __attribute__((ext_vector_type(8)));
typedef float f32x4 __attribute__((ext_vector_type(4)));
typedef short s16x4 __attribute__((ext_vector_type(4)));
typedef unsigned short u16x8 __attribute__((ext_vector_type(8)));
typedef unsigned short u16x4 __attribute__((ext_vector_type(4)));

__device__ __forceinline__ unsigned short f2bf(float f) {
  unsigned int u = __builtin_bit_cast(unsigned int, f);
  u += 0x7FFFu + ((u >> 16) & 1u);   // round-to-nearest-even
  return (unsigned short)(u >> 16);
}

__device__ __forceinline__ f32x4 mfma32(bf16x8 a, bf16x8 b, f32x4 c) {
  return __builtin_amdgcn_mfma_f32_16x16x32_bf16(a, b, c, 0, 0, 0);
}
__device__ __forceinline__ f32x4 mfma16(s16x4 a, s16x4 b, f32x4 c) {
  return __builtin_amdgcn_mfma_f32_16x16x16bf16_1k(a, b, c, 0, 0, 0);
}

// async global->LDS, 16B per lane. LDS dest must be wave-uniform base
// (HW adds lane*16); global src is per-lane.
__device__ __forceinline__ void gl16(const unsigned short* gsrc,
                                     unsigned short* lds) {
  __builtin_amdgcn_global_load_lds(
      (const __attribute__((address_space(1))) unsigned int*)gsrc,
      (__attribute__((address_space(3))) unsigned int*)lds, 16, 0, 0);
}

// ---- fused converts: z<4 -> Wt[z][n][k] = bf16(W[k][n]); z==4 -> X->bf16 ---
__global__ __launch_bounds__(256) void cvt_all(
    const float* __restrict__ x,
    const float* __restrict__ Wq, const float* __restrict__ Wk,
    const float* __restrict__ Wv, const float* __restrict__ Wo,
    unsigned short* __restrict__ xb, unsigned short* __restrict__ Wt) {
  const int z = blockIdx.z;
  const int tx = threadIdx.x, ty = threadIdx.y;    // 32 x 8
  if (z == 4) {
    const int tid = (blockIdx.y * 32 + blockIdx.x) * 256 + ty * 32 + tx;
#pragma unroll
    for (int it = 0; it < 4; ++it) {
      const int i = tid + it * 262144;
      const float4 v = ((const float4*)x)[i];
      u16x4 o = { f2bf(v.x), f2bf(v.y), f2bf(v.z), f2bf(v.w) };
      *(u16x4*)(xb + (size_t)i * 4) = o;
    }
    return;
  }
  const float* W = (z == 0) ? Wq : (z == 1) ? Wk : (z == 2) ? Wv : Wo;
  unsigned short* dst = Wt + (size_t)z * 1024 * 1024;
  __shared__ float t[32][33];
  const int n0 = blockIdx.x * 32, k0 = blockIdx.y * 32;
#pragma unroll
  for (int i = 0; i < 32; i += 8)
    t[ty + i][tx] = W[(size_t)(k0 + ty + i) * 1024 + n0 + tx];
  __syncthreads();
#pragma unroll
  for (int i = 0; i < 32; i += 8)
    dst[(size_t)(n0 + ty + i) * 1024 + k0 + tx] = f2bf(t[tx][ty + i]);
}

// ------------- bf16 MFMA GEMM: C[M,N] = A[M,1024] * Bt[N,1024]^T ------------
// 128xBN tile, BK=64, 4 waves (2x2), 2-phase global_load_lds staging.
// LDS rows = 64 elems = 128B = 8 chunks of 16B; element (row, kc) stored at
// chunk-field kc ^ (row&7). One gl16 = 8 rows: lane l -> dest row0+(l>>3),
// cf l&7 => source kc = (l&7)^((l>>3)&7) (row0 8-aligned). Frag read for
// (row = 16aligned+lq, kc = kk*4+lg): cf = (kk*4+lg)^(lq&7) -> 8 lanes per
// bank-group = structural b128 minimum, 0 conflicts.
// MODE 0 (BN=128): QKV. bias; q scaled 1/8; q,k,v -> [B,H,S,Dh]
// MODE 1 (BN=64):  out-proj. + bo, fp32 store.
template <int BN, int MODE>
__global__ __launch_bounds__(256) void gemm_lds(
    const unsigned short* __restrict__ A, const unsigned short* __restrict__ Bt,
    const float* __restrict__ bq, const float* __restrict__ bk,
    const float* __restrict__ bv,
    unsigned short* __restrict__ q_ws, unsigned short* __restrict__ k_ws,
    unsigned short* __restrict__ v_ws,
    const float* __restrict__ bo, float* __restrict__ outp) {
  constexpr int ACC_N = BN / 32;
  constexpr int BI = BN / 32;                      // B gl16 insts per wave
  __shared__ __align__(16) unsigned short Alds[128 * 64];
  __shared__ __align__(16) unsigned short Blds[BN * 64];
  const int tid = threadIdx.x, lane = tid & 63, w = tid >> 6;
  const int lq = lane & 15, lg = lane >> 4;
  const int bm = blockIdx.x, bn = blockIdx.y;
  const int wr = (w >> 1) * 64, wc = (w & 1) * (BN / 2);

  // staging: wave w stages A rows w*32..w*32+31 (4 insts of 8 rows) and
  // B rows w*(BN/4).. (BI insts). source k pre-swizzled per lane.
  const int lrow = lane >> 3;                      // row within 8-row chunk
  const int ksw = (((lane & 7) ^ lrow) << 3);      // source k offset (elems)
  const unsigned short* Ag =
      A + (size_t)(bm * 128 + w * 32 + lrow) * 1024 + ksw;
  const unsigned short* Bg =
      Bt + (size_t)(bn * BN + w * (BN / 4) + lrow) * 1024 + ksw;
  unsigned short* AlW = Alds + (w * 32) * 64;      // wave-uniform LDS bases
  unsigned short* BlW = Blds + (w * (BN / 4)) * 64;

  // frag reads: chunk-field = (kk*4+lg) ^ (lq&7)
  const int cs = lq & 7;

  f32x4 acc[4][ACC_N] = {};
  for (int kt = 0; kt < 1024; kt += 64) {
    __syncthreads();          // all waves done reading LDS from previous iter
#pragma unroll
    for (int i = 0; i < 4; ++i)
      gl16(Ag + kt + (size_t)i * 8 * 1024, AlW + i * 8 * 64);
#pragma unroll
    for (int i = 0; i < BI; ++i)
      gl16(Bg + kt + (size_t)i * 8 * 1024, BlW + i * 8 * 64);
    __syncthreads();          // drains vmcnt -> staged data visible
#pragma unroll
    for (int kk = 0; kk < 2; ++kk) {
      bf16x8 af[4], bfr[ACC_N];
#pragma unroll
      for (int m = 0; m < 4; ++m)
        af[m] = *(const bf16x8*)(Alds + (wr + m * 16 + lq) * 64 +
                                 (((kk * 4 + lg) ^ cs) << 3));
#pragma unroll
      for (int n = 0; n < ACC_N; ++n)
        bfr[n] = *(const bf16x8*)(Blds + (wc + n * 16 + lq) * 64 +
                                  (((kk * 4 + lg) ^ cs) << 3));
#pragma unroll
      for (int m = 0; m < 4; ++m)
#pragma unroll
        for (int n = 0; n < ACC_N; ++n)
          acc[m][n] = mfma32(af[m], bfr[n], acc[m][n]);
    }
  }

  // epilogue: C/D layout (m89): col = lane&15, row = (lane>>4)*4 + reg
  const int r0 = bm * 128 + wr + lg * 4;
  const int c0g = bn * BN + wc + lq;
#pragma unroll
  for (int m = 0; m < 4; ++m) {
#pragma unroll
    for (int n = 0; n < ACC_N; ++n) {
      const int col = c0g + n * 16;
#pragma unroll
      for (int j = 0; j < 4; ++j) {
        const int row = r0 + m * 16 + j;
        float v = acc[m][n][j];
        if (MODE == 0) {
          const int t = col >> 10, cc = col & 1023;
          const float* bias = (t == 0) ? bq : ((t == 1) ? bk : bv);
          v += bias[cc];
          if (t == 0) v *= 0.125f;  // bake in 1/sqrt(Dh)
          unsigned short* dst = (t == 0) ? q_ws : ((t == 1) ? k_ws : v_ws);
          const int h = cc >> 6, dh = cc & 63, b = row >> 11, s = row & 2047;
          dst[((size_t)(b * 16 + h) * 2048 + s) * 64 + dh] = f2bf(v);
        } else {
          outp[(size_t)row * 1024 + col] = v + bo[col];
        }
      }
    }
  }
}

// ---------------- banded flash attention (r8: static-max softmax) -----------
// One wave per 16-query strip; 4 waves/block. Swapped QK^T: S^T = K*Q^T so
// lane owns q = lane&15. STATIC-max softmax: p = exp(s - 4) (shift-exact;
// scores ~N(0,0.41), global max ~2.3 << 4). PV: O^T = V^T * P^T via 16x16x16;
// V gathered scalar from [B,H,S,Dh]. Masked lanes get p=0 explicitly.
__global__ __launch_bounds__(256) void attn_kernel(
    const unsigned short* __restrict__ q_ws,
    const unsigned short* __restrict__ k_ws,
    const unsigned short* __restrict__ v_ws,
    unsigned short* __restrict__ attn_out) {
  __shared__ unsigned short o_lds[4][16 * 64];
  const int tid = threadIdx.x, lane = tid & 63, w = tid >> 6;
  const int lq = lane & 15, lg = lane >> 4;
  const int bh = blockIdx.y;                       // b*16 + h
  const int q0 = blockIdx.x * 64 + w * 16;
  const unsigned short* Q = q_ws + (size_t)bh * 2048 * 64;
  const unsigned short* Kp = k_ws + (size_t)bh * 2048 * 64;
  const unsigned short* Vp = v_ws + (size_t)bh * 2048 * 64;

  const bf16x8 qf0 = *(const bf16x8*)(Q + (size_t)(q0 + lq) * 64 + lg * 8);
  const bf16x8 qf1 = *(const bf16x8*)(Q + (size_t)(q0 + lq) * 64 + 32 + lg * 8);

  float lsum = 0.f;
  f32x4 oacc[4] = {};
  int t0 = (q0 - 255) >> 4;
  if (t0 < 0) t0 = 0;
  const int t1 = q0 >> 4;

  for (int t = t0; t <= t1; ++t) {
    const int j0 = t * 16;
    const bf16x8 kf0 = *(const bf16x8*)(Kp + (size_t)(j0 + lq) * 64 + lg * 8);
    const bf16x8 kf1 =
        *(const bf16x8*)(Kp + (size_t)(j0 + lq) * 64 + 32 + lg * 8);
    f32x4 stv = {};
    stv = mfma32(kf0, qf0, stv);
    stv = mfma32(kf1, qf1, stv);   // S^T: col=q=lq, row=key=j0+lg*4+reg

    float p[4], ps = 0.f;
#pragma unroll
    for (int r = 0; r < 4; ++r) {
      const int delta = (q0 + lq) - (j0 + lg * 4 + r);
      const bool ok = (delta >= 0) && (delta < 256);
      p[r] = ok ? __expf(stv[r] - 4.0f) : 0.f;
      ps += p[r];
    }
    ps += __shfl_xor(ps, 16);
    ps += __shfl_xor(ps, 32);
    lsum += ps;

    s16x4 pb = { (short)f2bf(p[0]), (short)f2bf(p[1]),
                 (short)f2bf(p[2]), (short)f2bf(p[3]) };
#pragma unroll
    for (int c = 0; c < 4; ++c) {
      s16x4 vf;
#pragma unroll
      for (int j = 0; j < 4; ++j)
        vf[j] = (short)Vp[(size_t)(j0 + lg * 4 + j) * 64 + c * 16 + lq];
      oacc[c] = mfma16(vf, pb, oacc[c]);
    }
  }

  const float rl = 1.f / lsum;
#pragma unroll
  for (int c = 0; c < 4; ++c)
#pragma unroll
    for (int r = 0; r < 4; ++r)
      o_lds[w][lq * 64 + c * 16 + lg * 4 + r] = f2bf(oacc[c][r] * rl);
  __syncthreads();
  const int row = lane >> 2, d0 = (lane & 3) * 16;
  const u16x8 o0 = *(const u16x8*)(&o_lds[w][row * 64 + d0]);
  const u16x8 o1 = *(const u16x8*)(&o_lds[w][row * 64 + d0 + 8]);
  const size_t g =
      ((size_t)((bh >> 4) * 2048 + q0 + row)) * 1024 + (bh & 15) * 64 + d0;
  *(u16x8*)(attn_out + g) = o0;
  *(u16x8*)(attn_out + g + 8) = o1;
}

// ---------------------------------------------------------------------------
extern "C" void kernel_launch(void* const* d_in, const int* in_sizes, int n_in,
                              void* d_out, int out_size, void* d_ws,
                              size_t ws_size, hipStream_t stream) {
  const float* query = (const float*)d_in[0];
  const float* Wq = (const float*)d_in[1];
  const float* bq = (const float*)d_in[2];
  const float* Wk = (const float*)d_in[3];
  const float* bk = (const float*)d_in[4];
  const float* Wv = (const float*)d_in[5];
  const float* bv = (const float*)d_in[6];
  const float* Wo = (const float*)d_in[7];
  const float* bo = (const float*)d_in[8];
  float* outp = (float*)d_out;

  char* ws = (char*)d_ws;
  unsigned short* xbf = (unsigned short*)(ws);               // 8 MiB; reused as attn_out
  unsigned short* wt  = (unsigned short*)(ws + (8u << 20));  // 8 MiB (4 weights^T)
  unsigned short* qws = (unsigned short*)(ws + (16u << 20)); // 8 MiB
  unsigned short* kws = (unsigned short*)(ws + (24u << 20)); // 8 MiB
  unsigned short* vws = (unsigned short*)(ws + (32u << 20)); // 8 MiB

  cvt_all<<<dim3(32, 32, 5), dim3(32, 8), 0, stream>>>(query, Wq, Wk, Wv, Wo,
                                                       xbf, wt);
  // fused QKV: N = 3072, 128x128 tiles
  gemm_lds<128, 0><<<dim3(32, 24), 256, 0, stream>>>(
      xbf, wt, bq, bk, bv, qws, kws, vws, nullptr, nullptr);
  attn_kernel<<<dim3(32, 32), 256, 0, stream>>>(qws, kws, vws, xbf);
  // output projection: N = 1024, 128x64 tile -> 512 blocks (2/CU)
  gemm_lds<64, 1><<<dim3(32, 16), 256, 0, stream>>>(
      xbf, wt + (size_t)3 * 1024 * 1024, nullptr, nullptr, nullptr, nullptr,
      nullptr, nullptr, bo, outp);
}